// Round 9
// baseline (600.188 us; speedup 1.0000x reference)
//
#include <hip/hip_runtime.h>
#include <hip/hip_bf16.h>

#define NN 20000
#define NE 640000

typedef __attribute__((ext_vector_type(8))) short short8v;   // 8 bf16
typedef __attribute__((ext_vector_type(4))) float float4v;

__device__ __forceinline__ float silu_f(float x) {
    return x / (1.0f + __expf(-x));
}

__device__ __forceinline__ unsigned int f2bf16(float f) {
    __hip_bfloat16 b = __float2bfloat16(f);
    return (unsigned int)*(unsigned short*)&b;
}

__device__ __forceinline__ float bfpick(unsigned int v, bool odd) {
    return odd ? __uint_as_float(v & 0xffff0000u) : __uint_as_float(v << 16);
}

__device__ __forceinline__ float bf16u2f(unsigned short s) {
    return __uint_as_float(((unsigned int)s) << 16);
}

// ---------------------------------------------------------------------------
// Kernel A1: per-node y precompute -> PACKED BF16, plane-major.
// yrow uint [pl*16 + (u>>1)], half by u&1. 9 planes: y0, y1 m(3), y2 m(5).
// ---------------------------------------------------------------------------
__global__ __launch_bounds__(256) void node_y(
    const float* __restrict__ x,
    const float* __restrict__ W10,
    const float* __restrict__ W11,
    const float* __restrict__ W12,
    unsigned int* __restrict__ yAll16)
{
    __shared__ float xs[8][288];
    __shared__ float w10[1024];
    __shared__ float w11[1024];
    __shared__ float w12[1024];
    const int tid = threadIdx.x;
    const int nodeBase = blockIdx.x * 8;

    for (int i = tid; i < 1024; i += 256) { w10[i] = W10[i]; w11[i] = W11[i]; w12[i] = W12[i]; }
    for (int i = tid; i < 8 * 288; i += 256) {
        int nl = i / 288, c = i % 288;
        int n = nodeBase + nl;
        xs[nl][c] = (n < NN) ? x[(long)n * 288 + c] : 0.f;
    }
    __syncthreads();

    const int nl = tid >> 5, v = tid & 31;
    const int n = nodeBase + nl;
    if (n >= NN) return;

    const float inv_mul = 0.17677669529663687f;  // 1/sqrt(32)
    float vals[9];

    {
        float a = 0.f;
        #pragma unroll
        for (int u = 0; u < 32; ++u) a += xs[nl][u] * w10[u * 32 + v];
        vals[0] = a;
    }
    {
        float a0 = 0.f, a1 = 0.f, a2 = 0.f;
        #pragma unroll
        for (int u = 0; u < 32; ++u) {
            float wv = w11[u * 32 + v];
            a0 += xs[nl][32 + u * 3 + 0] * wv;
            a1 += xs[nl][32 + u * 3 + 1] * wv;
            a2 += xs[nl][32 + u * 3 + 2] * wv;
        }
        vals[1] = a0; vals[2] = a1; vals[3] = a2;
    }
    {
        float a[5] = {0.f, 0.f, 0.f, 0.f, 0.f};
        #pragma unroll
        for (int u = 0; u < 32; ++u) {
            float wv = w12[u * 32 + v];
            #pragma unroll
            for (int m = 0; m < 5; ++m) a[m] += xs[nl][128 + u * 5 + m] * wv;
        }
        #pragma unroll
        for (int m = 0; m < 5; ++m) vals[4 + m] = a[m];
    }

    unsigned int* yrow = yAll16 + (long)n * 144;
    const bool evenLane = ((v & 1) == 0);
    #pragma unroll
    for (int pl = 0; pl < 9; ++pl) {
        float mine  = vals[pl] * inv_mul;
        float other = __shfl_xor(mine, 1);
        if (evenLane)
            yrow[pl * 16 + (v >> 1)] = f2bf16(mine) | (f2bf16(other) << 16);
    }
}

// ---------------------------------------------------------------------------
// Kernel A2: sc GEMM. 64 nodes/block; thread = 8 nodes x 3 cols.
// ---------------------------------------------------------------------------
__global__ __launch_bounds__(256) void node_sc(
    const float* __restrict__ x,
    const float* __restrict__ na,
    const float* __restrict__ scW,
    float* __restrict__ sc)
{
    __shared__ float B[128 * 96];
    __shared__ float x0s[64 * 32];
    __shared__ float nas[64 * 4];
    const int tid = threadIdx.x;
    const int nodeBase = blockIdx.x * 64;

    for (int i = tid; i < 12288; i += 256) {
        int h = i >> 12, r = i & 4095;
        int u = r >> 7, r2 = r & 127;
        int t = r2 >> 5, w = r2 & 31;
        B[(u * 4 + t) * 96 + h * 32 + w] = scW[i];
    }
    for (int i = tid; i < 2048; i += 256) {
        int nl = i >> 5, u = i & 31;
        int n = nodeBase + nl;
        x0s[i] = (n < NN) ? x[(long)n * 288 + u] : 0.f;
    }
    for (int i = tid; i < 256; i += 256) {
        int nl = i >> 2, t = i & 3;
        int n = nodeBase + nl;
        nas[i] = (n < NN) ? na[n * 4 + t] : 0.f;
    }
    __syncthreads();

    const int g = tid >> 5, c = tid & 31;
    float nav[8][4];
    #pragma unroll
    for (int j = 0; j < 8; ++j)
        #pragma unroll
        for (int t = 0; t < 4; ++t) nav[j][t] = nas[(g * 8 + j) * 4 + t];

    float acc[3][8];
    #pragma unroll
    for (int cc = 0; cc < 3; ++cc)
        #pragma unroll
        for (int j = 0; j < 8; ++j) acc[cc][j] = 0.f;

    for (int u = 0; u < 32; ++u) {
        float aj[8];
        #pragma unroll
        for (int j = 0; j < 8; ++j) aj[j] = x0s[(g * 8 + j) * 32 + u];
        #pragma unroll
        for (int t = 0; t < 4; ++t) {
            float b0 = B[(u * 4 + t) * 96 + c];
            float b1 = B[(u * 4 + t) * 96 + 32 + c];
            float b2 = B[(u * 4 + t) * 96 + 64 + c];
            #pragma unroll
            for (int j = 0; j < 8; ++j) {
                float p = aj[j] * nav[j][t];
                acc[0][j] += p * b0;
                acc[1][j] += p * b1;
                acc[2][j] += p * b2;
            }
        }
    }

    const float inv_sc = 0.08838834764831845f;  // 1/sqrt(128)
    #pragma unroll
    for (int j = 0; j < 8; ++j) {
        int n = nodeBase + g * 8 + j;
        if (n < NN) {
            #pragma unroll
            for (int cc = 0; cc < 3; ++cc)
                sc[((long)cc * NN + n) * 32 + c] = acc[cc][j] * inv_sc;
        }
    }
}

// ---------------------------------------------------------------------------
// CSR builds: generic histogram + scan; scatter by source (edge-id list) and
// by dest (per-edge dest-sorted position).
// ---------------------------------------------------------------------------
__global__ __launch_bounds__(256) void hist_kernel(
    const int* __restrict__ keys, int* __restrict__ counts)
{
    int e = blockIdx.x * 256 + threadIdx.x;
    if (e < NE) atomicAdd(&counts[keys[e]], 1);
}

__global__ __launch_bounds__(1024) void scan_kernel(
    const int* __restrict__ counts, int* __restrict__ offsets)
{
    __shared__ int partial[1024];
    const int t = threadIdx.x;
    const int base = t * 20;          // 1024*20 = 20480 >= NN
    int loc[20];
    int s = 0;
    #pragma unroll
    for (int i = 0; i < 20; ++i) {
        int v = (base + i < NN) ? counts[base + i] : 0;
        loc[i] = s;
        s += v;
    }
    partial[t] = s;
    __syncthreads();
    for (int off = 1; off < 1024; off <<= 1) {
        int v = (t >= off) ? partial[t - off] : 0;
        __syncthreads();
        partial[t] += v;
        __syncthreads();
    }
    int pre = (t == 0) ? 0 : partial[t - 1];
    #pragma unroll
    for (int i = 0; i < 20; ++i)
        if (base + i <= NN) offsets[base + i] = pre + loc[i];
}

__global__ __launch_bounds__(256) void scatter_src(
    const int* __restrict__ skeys, const int* __restrict__ offsets,
    int* __restrict__ cursor, int* __restrict__ ssidx)
{
    int e = blockIdx.x * 256 + threadIdx.x;
    if (e < NE) {
        int s = skeys[e];
        int pos = offsets[s] + atomicAdd(&cursor[s], 1);
        ssidx[pos] = e;
    }
}

__global__ __launch_bounds__(256) void scatter_dst(
    const int* __restrict__ dkeys, const int* __restrict__ offsets,
    int* __restrict__ cursor, int* __restrict__ dstpos)
{
    int e = blockIdx.x * 256 + threadIdx.x;
    if (e < NE) {
        int d = dkeys[e];
        int pos = offsets[d] + atomicAdd(&cursor[d], 1);
        dstpos[e] = pos;
    }
}

// ---------------------------------------------------------------------------
// Kernel B (fused): for 64 SOURCE-sorted edges: h = silu(ee@Wm0/sqrt8);
// w = h @ Wm1' (MFMA, per-class scale folded into Wm1 fragments);
// m = w * f(y[src], ea)  (y reads are L1/L2-hot: consecutive edges share src);
// msg row scatter-written to dest-sorted position dstpos[e].
// ---------------------------------------------------------------------------
__global__ __launch_bounds__(256) void edge_msg(
    const float* __restrict__ ee,
    const float* __restrict__ ea,
    const int*   __restrict__ ei,
    const int*   __restrict__ ssidx,
    const int*   __restrict__ dstpos,
    const float* __restrict__ Wm0,
    const float* __restrict__ Wm1,
    const unsigned int* __restrict__ yAll16,
    unsigned int* __restrict__ msg)
{
    __shared__ float ees[64 * 8];                 // [le*8 + k]
    __shared__ float eas[64 * 10];                // [le*10 + k], padded
    __shared__ float wm0s[512];                   // [k*64 + i]
    __shared__ unsigned short hsf[8 * 64 * 8];    // A-frags
    __shared__ unsigned short wm1f[12 * 64 * 8];  // B-frags (scaled)
    __shared__ unsigned int wtile[64 * 48];       // w then m, bf16x2 packed
    __shared__ int srcs[64];
    __shared__ int dstp[64];

    const int tid = threadIdx.x;
    const long pb = (long)blockIdx.x * 64;        // source-sorted base

    // staging (ssidx re-read is L1-hot)
    if (tid < 64) {
        int e = ssidx[pb + tid];
        srcs[tid] = ei[e];
        dstp[tid] = dstpos[e];
    }
    for (int i = tid; i < 512; i += 256) wm0s[i] = Wm0[i];
    for (int i = tid; i < 512; i += 256) {
        int e = ssidx[pb + (i >> 3)];
        ees[i] = ee[(long)e * 8 + (i & 7)];
    }
    for (int i = tid; i < 576; i += 256) {
        int le = i / 9, k = i % 9;
        int e = ssidx[pb + le];
        eas[le * 10 + k] = ea[(long)e * 9 + k];
    }
    // Wm1 -> B-frag order, bf16, per-channel-class scale folded:
    // nt 0,1 -> m0-class, 2,3 -> m1-class, 4,5 -> m2-class
    {
        const float sNT[6] = {0.022097086912079608f, 0.022097086912079608f,
                              0.012757759076995719f, 0.012757759076995719f,
                              0.009882117688026186f, 0.009882117688026186f};
        for (int idx = tid; idx < 6144; idx += 256) {
            int j = idx & 7, lane = (idx >> 3) & 63, sec = idx >> 9;
            int kh = sec / 6, nt = sec % 6;
            int k = kh * 32 + ((lane >> 4) * 8) + j;
            int n = nt * 16 + (lane & 15);
            wm1f[idx] = (unsigned short)f2bf16(Wm1[k * 96 + n] * sNT[nt]);
        }
    }
    __syncthreads();

    // phase 1: h -> A-frag slots (bf16)
    {
        const float inv_sqrt8 = 0.35355339059327373f;
        const int e = tid >> 2, i0 = (tid & 3) * 16;
        const int tile = e >> 4, m = e & 15;
        float emb[8];
        #pragma unroll
        for (int k = 0; k < 8; ++k) emb[k] = ees[e * 8 + k];
        #pragma unroll
        for (int i = 0; i < 16; ++i) {
            int k = i0 + i;
            float t = 0.f;
            #pragma unroll
            for (int q = 0; q < 8; ++q) t += emb[q] * wm0s[q * 64 + k];
            int kh = k >> 5, kq = (k >> 3) & 3, j = k & 7;
            int lane = kq * 16 + m;
            hsf[((tile * 2 + kh) * 64 + lane) * 8 + j] =
                (unsigned short)f2bf16(silu_f(t * inv_sqrt8));
        }
    }
    __syncthreads();

    // phase 2: MFMA -> wtile (rows = edges, cols = channels, bf16 shorts)
    {
        unsigned short* wts = (unsigned short*)wtile;
        const int wv = tid >> 6, lane = tid & 63;
        const short8v a0 = *(const short8v*)&hsf[((wv * 2 + 0) * 64 + lane) * 8];
        const short8v a1 = *(const short8v*)&hsf[((wv * 2 + 1) * 64 + lane) * 8];
        const int col = lane & 15, rowq = (lane >> 4) * 4;
        #pragma unroll
        for (int nt = 0; nt < 6; ++nt) {
            short8v b0 = *(const short8v*)&wm1f[((0 * 6 + nt) * 64 + lane) * 8];
            short8v b1 = *(const short8v*)&wm1f[((1 * 6 + nt) * 64 + lane) * 8];
            float4v acc = {0.f, 0.f, 0.f, 0.f};
            acc = __builtin_amdgcn_mfma_f32_16x16x32_bf16(a0, b0, acc, 0, 0, 0);
            acc = __builtin_amdgcn_mfma_f32_16x16x32_bf16(a1, b1, acc, 0, 0, 0);
            const int c = nt * 16 + col;
            #pragma unroll
            for (int r = 0; r < 4; ++r)
                wts[(wv * 16 + rowq + r) * 96 + c] = (unsigned short)f2bf16(acc[r]);
        }
    }
    __syncthreads();

    // phase 3: message formation in place. group g (32 lanes) x 8 edges.
    {
        unsigned short* wts = (unsigned short*)wtile;
        const int g = tid >> 5, u = tid & 31;
        const int p = u >> 1;
        const bool odd = (u & 1);
        #pragma unroll 2
        for (int r = 0; r < 8; ++r) {
            const int le = g * 8 + r;
            const unsigned int* yb = yAll16 + (long)srcs[le] * 144;
            const float* ev = &eas[le * 10];

            float w0 = bf16u2f(wts[le * 96 + u]);
            float w1 = bf16u2f(wts[le * 96 + 32 + u]);
            float w2 = bf16u2f(wts[le * 96 + 64 + u]);

            float m0 = w0 * bfpick(yb[p], odd) * ev[0];

            float d1 = bfpick(yb[16 + p], odd) * ev[1]
                     + bfpick(yb[32 + p], odd) * ev[2]
                     + bfpick(yb[48 + p], odd) * ev[3];
            float m1 = w1 * d1;

            float d2 = bfpick(yb[64 + p], odd) * ev[4]
                     + bfpick(yb[80 + p], odd) * ev[5]
                     + bfpick(yb[96 + p], odd) * ev[6]
                     + bfpick(yb[112 + p], odd) * ev[7]
                     + bfpick(yb[128 + p], odd) * ev[8];
            float m2 = w2 * d2;

            wts[le * 96 + u]      = (unsigned short)f2bf16(m0);
            wts[le * 96 + 32 + u] = (unsigned short)f2bf16(m1);
            wts[le * 96 + 64 + u] = (unsigned short)f2bf16(m2);
        }
    }
    __syncthreads();

    // phase 4: scatter rows to dest-sorted positions (192 B contiguous/row)
    for (int i = tid; i < 3072; i += 256) {
        int row = i / 48, q = i % 48;
        msg[(long)dstp[row] * 48 + q] = wtile[row * 48 + q];
    }
}

// ---------------------------------------------------------------------------
// Kernel B2: pure sequential segment-sum of msg rows per node. No gather.
// ---------------------------------------------------------------------------
__global__ __launch_bounds__(256) void gather2(
    const unsigned int* __restrict__ msg,
    const int* __restrict__ offsets,
    float* __restrict__ mid)
{
    const int tid = threadIdx.x;
    const int n = blockIdx.x * 8 + (tid >> 5);
    const int u = tid & 31;
    if (n >= NN) return;

    const int lo = offsets[n], hi = offsets[n + 1];
    const int p = u >> 1;
    const bool odd = (u & 1);

    float acc0 = 0.f, acc1 = 0.f, acc2 = 0.f;
    #pragma unroll 4
    for (int j = lo; j < hi; ++j) {
        const unsigned int* wr = msg + (long)j * 48;
        acc0 += bfpick(wr[p], odd);
        acc1 += bfpick(wr[16 + p], odd);
        acc2 += bfpick(wr[32 + p], odd);
    }

    float* midRow = mid + (long)n * 96;
    midRow[u]      = acc0;
    midRow[32 + u] = acc1;
    midRow[64 + u] = acc2;
}

// ---------------------------------------------------------------------------
// Kernel C: output GEMV + sc + silu.
// ---------------------------------------------------------------------------
__global__ __launch_bounds__(256) void node_out(
    const float* __restrict__ mid,
    const float* __restrict__ sc,
    const float* __restrict__ L0,
    const float* __restrict__ L1,
    const float* __restrict__ L2,
    float* __restrict__ out)
{
    __shared__ float l0[32 * 32];
    __shared__ float l1[64 * 32];
    __shared__ float l2[96 * 32];
    __shared__ float ms[8][96];
    const int tid = threadIdx.x;
    const int nodeBase = blockIdx.x * 8;

    for (int i = tid; i < 1024; i += 256) l0[i] = L0[i];
    for (int i = tid; i < 2048; i += 256) l1[i] = L1[i];
    for (int i = tid; i < 3072; i += 256) l2[i] = L2[i];
    for (int i = tid; i < 768; i += 256) {
        int nl = i / 96, c = i % 96;
        int n = nodeBase + nl;
        ms[nl][c] = (n < NN) ? mid[(long)n * 96 + c] : 0.f;
    }
    __syncthreads();

    const int nl = tid >> 5, wv = tid & 31;
    const int n = nodeBase + nl;
    if (n >= NN) return;

    float a0 = 0.f, a1 = 0.f, a2 = 0.f;
    #pragma unroll
    for (int u = 0; u < 32; ++u) {
        float m = ms[nl][u];
        a0 += m * l0[u * 32 + wv];
        a1 += m * l1[u * 32 + wv];
        a2 += m * l2[u * 32 + wv];
    }
    #pragma unroll
    for (int u = 32; u < 64; ++u) {
        float m = ms[nl][u];
        a1 += m * l1[u * 32 + wv];
        a2 += m * l2[u * 32 + wv];
    }
    #pragma unroll
    for (int u = 64; u < 96; ++u) a2 += ms[nl][u] * l2[u * 32 + wv];

    const float is32 = 0.17677669529663687f;
    const float is64 = 0.125f;
    const float is96 = 0.10206207261596575f;
    const long base = (long)n * 32 + wv;
    out[base]                     = silu_f(a0 * is32 + sc[base]);
    out[(long)NN * 32 + base]     = silu_f(a1 * is64 + sc[(long)NN * 32 + base]);
    out[(long)2 * NN * 32 + base] = silu_f(a2 * is96 + sc[(long)2 * NN * 32 + base]);
}

extern "C" void kernel_launch(void* const* d_in, const int* in_sizes, int n_in,
                              void* d_out, int out_size, void* d_ws, size_t ws_size,
                              hipStream_t stream)
{
    const float* x   = (const float*)d_in[0];
    const float* na  = (const float*)d_in[1];
    const float* ee  = (const float*)d_in[2];
    const float* ea  = (const float*)d_in[3];
    const int*   ei  = (const int*)d_in[4];
    const float* W10 = (const float*)d_in[5];
    const float* W11 = (const float*)d_in[6];
    const float* W12 = (const float*)d_in[7];
    const float* Wm0 = (const float*)d_in[8];
    const float* Wm1 = (const float*)d_in[9];
    const float* L0  = (const float*)d_in[10];
    const float* L1  = (const float*)d_in[11];
    const float* L2  = (const float*)d_in[12];
    const float* scW = (const float*)d_in[13];
    float* out = (float*)d_out;

    unsigned int* yAll16 = (unsigned int*)d_ws;           // NN*144 uints
    float* sc       = (float*)(yAll16 + (size_t)NN * 144);// 3*NN*32 f32
    float* mid      = sc + (size_t)3 * NN * 32;           // NN*96 f32
    int*   counts_s = (int*)(mid + (size_t)NN * 96);      // NN
    int*   offs_s   = counts_s + NN;                      // NN+1
    int*   cursor_s = offs_s + NN + 1;                    // NN
    int*   counts_d = cursor_s + NN;                      // NN
    int*   offs_d   = counts_d + NN;                      // NN+1
    int*   cursor_d = offs_d + NN + 1;                    // NN
    int*   ssidx    = cursor_d + NN;                      // NE
    int*   dstpos   = ssidx + NE;                         // NE
    unsigned int* msg = (unsigned int*)(dstpos + NE);     // NE*48 uints (123 MB)

    hipMemsetAsync(counts_s, 0, NN * sizeof(int), stream);
    hipMemsetAsync(cursor_s, 0, NN * sizeof(int), stream);
    hipMemsetAsync(counts_d, 0, NN * sizeof(int), stream);
    hipMemsetAsync(cursor_d, 0, NN * sizeof(int), stream);

    hist_kernel<<<(NE + 255) / 256, 256, 0, stream>>>(ei, counts_s);        // by source
    hist_kernel<<<(NE + 255) / 256, 256, 0, stream>>>(ei + NE, counts_d);   // by dest
    scan_kernel<<<1, 1024, 0, stream>>>(counts_s, offs_s);
    scan_kernel<<<1, 1024, 0, stream>>>(counts_d, offs_d);
    scatter_src<<<(NE + 255) / 256, 256, 0, stream>>>(ei, offs_s, cursor_s, ssidx);
    scatter_dst<<<(NE + 255) / 256, 256, 0, stream>>>(ei + NE, offs_d, cursor_d, dstpos);

    node_y<<<(NN + 7) / 8, 256, 0, stream>>>(x, W10, W11, W12, yAll16);
    node_sc<<<(NN + 63) / 64, 256, 0, stream>>>(x, na, scW, sc);

    edge_msg<<<NE / 64, 256, 0, stream>>>(ee, ea, ei, ssidx, dstpos,
                                          Wm0, Wm1, yAll16, msg);
    gather2<<<(NN + 7) / 8, 256, 0, stream>>>(msg, offs_d, mid);

    node_out<<<(NN + 7) / 8, 256, 0, stream>>>(mid, sc, L0, L1, L2, out);
}

// Round 10
// 464.662 us; speedup vs baseline: 1.2917x; 1.2917x over previous
//
#include <hip/hip_runtime.h>
#include <hip/hip_bf16.h>

#define NN 20000
#define NE 640000

typedef __attribute__((ext_vector_type(8))) short short8v;   // 8 bf16
typedef __attribute__((ext_vector_type(4))) float float4v;

__device__ __forceinline__ float silu_f(float x) {
    return x / (1.0f + __expf(-x));
}

__device__ __forceinline__ unsigned int f2bf16(float f) {
    __hip_bfloat16 b = __float2bfloat16(f);
    return (unsigned int)*(unsigned short*)&b;
}

__device__ __forceinline__ float bfpick(unsigned int v, bool odd) {
    return odd ? __uint_as_float(v & 0xffff0000u) : __uint_as_float(v << 16);
}

// ---------------------------------------------------------------------------
// prep_frags: Wm1 -> bf16 B-fragment image (0.125 folded), computed ONCE.
// idx = ((kh*6+nt)*64+lane)*8+j ; adjacent j packed into one uint.
// ---------------------------------------------------------------------------
__global__ __launch_bounds__(256) void prep_frags(
    const float* __restrict__ Wm1, unsigned int* __restrict__ wm1fg)
{
    int idx = blockIdx.x * 256 + threadIdx.x;     // 0..6143
    int j = idx & 7, lane = (idx >> 3) & 63, sec = idx >> 9;
    int kh = sec / 6, nt = sec % 6;
    int k = kh * 32 + ((lane >> 4) * 8) + j;
    int n = nt * 16 + (lane & 15);
    unsigned int b = f2bf16(Wm1[k * 96 + n] * 0.125f);
    unsigned int other = (unsigned int)__shfl_xor((int)b, 1);
    if ((idx & 1) == 0) wm1fg[idx >> 1] = b | (other << 16);
}

// ---------------------------------------------------------------------------
// Kernel A1: per-node y precompute -> PACKED BF16, plane-major (144 uints).
// float4-vectorized staging.
// ---------------------------------------------------------------------------
__global__ __launch_bounds__(256) void node_y(
    const float* __restrict__ x,
    const float* __restrict__ W10,
    const float* __restrict__ W11,
    const float* __restrict__ W12,
    unsigned int* __restrict__ yAll16)
{
    __shared__ float xs[8][288];
    __shared__ float w10[1024];
    __shared__ float w11[1024];
    __shared__ float w12[1024];
    const int tid = threadIdx.x;
    const int nodeBase = blockIdx.x * 8;

    if (tid < 256) {
        ((float4*)w10)[tid] = ((const float4*)W10)[tid];
        ((float4*)w11)[tid] = ((const float4*)W11)[tid];
        ((float4*)w12)[tid] = ((const float4*)W12)[tid];
    }
    for (int i = tid; i < 576; i += 256) {
        int nl = i / 72, q = i % 72;
        int n = nodeBase + nl;
        float4 v = {0.f, 0.f, 0.f, 0.f};
        if (n < NN) v = ((const float4*)(x + (long)n * 288))[q];
        ((float4*)xs[nl])[q] = v;
    }
    __syncthreads();

    const int nl = tid >> 5, v = tid & 31;
    const int n = nodeBase + nl;
    if (n >= NN) return;

    const float inv_mul = 0.17677669529663687f;  // 1/sqrt(32)
    float vals[9];

    {
        float a = 0.f;
        #pragma unroll
        for (int u = 0; u < 32; ++u) a += xs[nl][u] * w10[u * 32 + v];
        vals[0] = a;
    }
    {
        float a0 = 0.f, a1 = 0.f, a2 = 0.f;
        #pragma unroll
        for (int u = 0; u < 32; ++u) {
            float wv = w11[u * 32 + v];
            a0 += xs[nl][32 + u * 3 + 0] * wv;
            a1 += xs[nl][32 + u * 3 + 1] * wv;
            a2 += xs[nl][32 + u * 3 + 2] * wv;
        }
        vals[1] = a0; vals[2] = a1; vals[3] = a2;
    }
    {
        float a[5] = {0.f, 0.f, 0.f, 0.f, 0.f};
        #pragma unroll
        for (int u = 0; u < 32; ++u) {
            float wv = w12[u * 32 + v];
            #pragma unroll
            for (int m = 0; m < 5; ++m) a[m] += xs[nl][128 + u * 5 + m] * wv;
        }
        #pragma unroll
        for (int m = 0; m < 5; ++m) vals[4 + m] = a[m];
    }

    unsigned int* yrow = yAll16 + (long)n * 144;
    const bool evenLane = ((v & 1) == 0);
    #pragma unroll
    for (int pl = 0; pl < 9; ++pl) {
        float mine  = vals[pl] * inv_mul;
        float other = __shfl_xor(mine, 1);
        if (evenLane)
            yrow[pl * 16 + (v >> 1)] = f2bf16(mine) | (f2bf16(other) << 16);
    }
}

// ---------------------------------------------------------------------------
// Kernel A2: sc GEMM. 64 nodes/block; thread = 8 nodes x 3 cols.
// ---------------------------------------------------------------------------
__global__ __launch_bounds__(256) void node_sc(
    const float* __restrict__ x,
    const float* __restrict__ na,
    const float* __restrict__ scW,
    float* __restrict__ sc)
{
    __shared__ float B[128 * 96];
    __shared__ float x0s[64 * 32];
    __shared__ float nas[64 * 4];
    const int tid = threadIdx.x;
    const int nodeBase = blockIdx.x * 64;

    // scW[((h*32+u)*4+t)*32 + w] -> B[(u*4+t)*96 + h*32 + w], float4 chunks
    for (int i = tid; i < 3072; i += 256) {
        int qw = i & 7, rest = i >> 3;
        int t = rest & 3, u = (rest >> 2) & 31, h = rest >> 7;
        float4 v = ((const float4*)scW)[i];
        ((float4*)&B[(u * 4 + t) * 96 + h * 32])[qw] = v;
    }
    for (int i = tid; i < 512; i += 256) {
        int nl = i >> 3, q = i & 7;
        int n = nodeBase + nl;
        float4 v = {0.f, 0.f, 0.f, 0.f};
        if (n < NN) v = ((const float4*)(x + (long)n * 288))[q];
        ((float4*)&x0s[nl * 32])[q] = v;
    }
    for (int i = tid; i < 256; i += 256) {
        int nl = i >> 2, t = i & 3;
        int n = nodeBase + nl;
        nas[i] = (n < NN) ? na[n * 4 + t] : 0.f;
    }
    __syncthreads();

    const int g = tid >> 5, c = tid & 31;
    float nav[8][4];
    #pragma unroll
    for (int j = 0; j < 8; ++j)
        #pragma unroll
        for (int t = 0; t < 4; ++t) nav[j][t] = nas[(g * 8 + j) * 4 + t];

    float acc[3][8];
    #pragma unroll
    for (int cc = 0; cc < 3; ++cc)
        #pragma unroll
        for (int j = 0; j < 8; ++j) acc[cc][j] = 0.f;

    for (int u = 0; u < 32; ++u) {
        float aj[8];
        #pragma unroll
        for (int j = 0; j < 8; ++j) aj[j] = x0s[(g * 8 + j) * 32 + u];
        #pragma unroll
        for (int t = 0; t < 4; ++t) {
            float b0 = B[(u * 4 + t) * 96 + c];
            float b1 = B[(u * 4 + t) * 96 + 32 + c];
            float b2 = B[(u * 4 + t) * 96 + 64 + c];
            #pragma unroll
            for (int j = 0; j < 8; ++j) {
                float p = aj[j] * nav[j][t];
                acc[0][j] += p * b0;
                acc[1][j] += p * b1;
                acc[2][j] += p * b2;
            }
        }
    }

    const float inv_sc = 0.08838834764831845f;  // 1/sqrt(128)
    #pragma unroll
    for (int j = 0; j < 8; ++j) {
        int n = nodeBase + g * 8 + j;
        if (n < NN) {
            #pragma unroll
            for (int cc = 0; cc < 3; ++cc)
                sc[((long)cc * NN + n) * 32 + c] = acc[cc][j] * inv_sc;
        }
    }
}

// ---------------------------------------------------------------------------
// CSR build (dest): histogram -> scan -> scatter ids (+ sorted source).
// ---------------------------------------------------------------------------
__global__ __launch_bounds__(256) void hist_kernel(
    const int* __restrict__ ei, int* __restrict__ counts)
{
    int e = blockIdx.x * 256 + threadIdx.x;
    if (e < NE) atomicAdd(&counts[ei[NE + e]], 1);
}

__global__ __launch_bounds__(1024) void scan_kernel(
    const int* __restrict__ counts, int* __restrict__ offsets)
{
    __shared__ int partial[1024];
    const int t = threadIdx.x;
    const int base = t * 20;          // 1024*20 = 20480 >= NN
    int loc[20];
    int s = 0;
    #pragma unroll
    for (int i = 0; i < 20; ++i) {
        int v = (base + i < NN) ? counts[base + i] : 0;
        loc[i] = s;
        s += v;
    }
    partial[t] = s;
    __syncthreads();
    for (int off = 1; off < 1024; off <<= 1) {
        int v = (t >= off) ? partial[t - off] : 0;
        __syncthreads();
        partial[t] += v;
        __syncthreads();
    }
    int pre = (t == 0) ? 0 : partial[t - 1];
    #pragma unroll
    for (int i = 0; i < 20; ++i)
        if (base + i <= NN) offsets[base + i] = pre + loc[i];
}

__global__ __launch_bounds__(256) void scatter_ids(
    const int* __restrict__ ei, const int* __restrict__ offsets,
    int* __restrict__ cursor, int* __restrict__ sidx, int* __restrict__ ssrc)
{
    int e = blockIdx.x * 256 + threadIdx.x;
    if (e < NE) {
        int d = ei[NE + e];
        int s = ei[e];
        int pos = offsets[d] + atomicAdd(&cursor[d], 1);
        sidx[pos] = e;
        ssrc[pos] = s;
    }
}

// ---------------------------------------------------------------------------
// Kernel B1 (MFMA): w = silu(ee@Wm0/sqrt8) @ Wm1 * 0.125 for 128 sorted
// positions per block. Wm1 fragments precomputed (prep_frags) -> pure copy.
// ---------------------------------------------------------------------------
__global__ __launch_bounds__(256) void edge_w(
    const float* __restrict__ ee,
    const int*   __restrict__ sidx,
    const float* __restrict__ Wm0,
    const unsigned int* __restrict__ wm1fg,
    unsigned int* __restrict__ w)
{
    __shared__ float ees[128 * 8];                 // [le*8 + k]
    __shared__ float wm0s[512];                    // [k*64 + i]
    __shared__ unsigned short hsf[16 * 64 * 8];    // A-frags (8 edge-tiles x 2 kh)
    __shared__ unsigned int wm1u[3072];            // B-frags (packed)
    __shared__ unsigned int wtile[128 * 48];       // D, bf16x2 packed

    const int tid = threadIdx.x;
    const long pb = (long)blockIdx.x * 128;        // sorted position base

    for (int i = tid; i < 512; i += 256) wm0s[i] = Wm0[i];
    for (int i = tid; i < 3072; i += 256) wm1u[i] = wm1fg[i];
    for (int i = tid; i < 1024; i += 256) {
        int le = i >> 3, k = i & 7;
        int e = sidx[pb + le];
        ees[i] = ee[(long)e * 8 + k];
    }
    __syncthreads();

    // phase 1: h -> A-frag slots (bf16). thread = (edge, k-half)
    {
        const float inv_sqrt8 = 0.35355339059327373f;
        const int e = tid >> 1, kb = (tid & 1) * 32;
        const int tile = e >> 4, m = e & 15;
        float emb[8];
        #pragma unroll
        for (int k = 0; k < 8; ++k) emb[k] = ees[e * 8 + k];
        #pragma unroll
        for (int i = 0; i < 32; ++i) {
            int k = kb + i;
            float t = 0.f;
            #pragma unroll
            for (int q = 0; q < 8; ++q) t += emb[q] * wm0s[q * 64 + k];
            int kh = k >> 5, kq = (k >> 3) & 3, j = k & 7;
            int lane = kq * 16 + m;
            hsf[((tile * 2 + kh) * 64 + lane) * 8 + j] =
                (unsigned short)f2bf16(silu_f(t * inv_sqrt8));
        }
    }
    __syncthreads();

    // phase 2: MFMA. wave wv -> edge-tiles {2wv, 2wv+1} x 6 channel-tiles.
    {
        unsigned short* wts = (unsigned short*)wtile;
        const unsigned short* wm1f = (const unsigned short*)wm1u;
        const int wv = tid >> 6, lane = tid & 63;
        const int col = lane & 15, rowq = (lane >> 4) * 4;
        #pragma unroll
        for (int eti = 0; eti < 2; ++eti) {
            const int et = wv * 2 + eti;
            const short8v a0 = *(const short8v*)&hsf[((et * 2 + 0) * 64 + lane) * 8];
            const short8v a1 = *(const short8v*)&hsf[((et * 2 + 1) * 64 + lane) * 8];
            #pragma unroll
            for (int nt = 0; nt < 6; ++nt) {
                short8v b0 = *(const short8v*)&wm1f[((0 * 6 + nt) * 64 + lane) * 8];
                short8v b1 = *(const short8v*)&wm1f[((1 * 6 + nt) * 64 + lane) * 8];
                float4v acc = {0.f, 0.f, 0.f, 0.f};
                acc = __builtin_amdgcn_mfma_f32_16x16x32_bf16(a0, b0, acc, 0, 0, 0);
                acc = __builtin_amdgcn_mfma_f32_16x16x32_bf16(a1, b1, acc, 0, 0, 0);
                const int c = nt * 16 + col;
                #pragma unroll
                for (int r = 0; r < 4; ++r)
                    wts[(et * 16 + rowq + r) * 96 + c] =
                        (unsigned short)f2bf16(acc[r]);
            }
        }
    }
    __syncthreads();

    // copy-out: 128 rows x 48 uints, coalesced, contiguous at sorted base
    for (int i = tid; i < 6144; i += 256)
        w[pb * 48 + i] = wtile[i];
}

// ---------------------------------------------------------------------------
// Kernel B2: single-pass atomic-free gather-reduce (R8-proven).
// ---------------------------------------------------------------------------
__global__ __launch_bounds__(256) void gather_reduce(
    const unsigned int* __restrict__ w,
    const float* __restrict__ ea,
    const int*   __restrict__ ssrc,
    const unsigned int* __restrict__ yAll16,
    const int*   __restrict__ sidx,
    const int*   __restrict__ offsets,
    float* __restrict__ mid)
{
    const int tid = threadIdx.x;
    const int n = blockIdx.x * 8 + (tid >> 5);
    const int u = tid & 31;
    if (n >= NN) return;

    const int lo = offsets[n], hi = offsets[n + 1];

    const float invAVG = 0.17677669529663687f;                        // 1/sqrt(32)
    const float c1     = 0.5773502691896258f * 0.17677669529663687f;  // /sqrt3/sqrt32
    const float c2     = 0.4472135954999579f * 0.17677669529663687f;  // /sqrt5/sqrt32

    const int p = u >> 1;
    const bool odd = (u & 1);

    float acc0 = 0.f, acc1 = 0.f, acc2 = 0.f;
    #pragma unroll 2
    for (int j = lo; j < hi; ++j) {
        const int e = sidx[j];
        const int s = ssrc[j];
        const unsigned int* wr = w + (long)j * 48;
        const unsigned int* yb = yAll16 + (long)s * 144;
        const float* eav = ea + (long)e * 9;

        float w0 = bfpick(wr[p], odd);
        float w1 = bfpick(wr[16 + p], odd);
        float w2 = bfpick(wr[32 + p], odd);

        acc0 += w0 * bfpick(yb[p], odd) * eav[0];

        float d1 = bfpick(yb[16 + p], odd) * eav[1]
                 + bfpick(yb[32 + p], odd) * eav[2]
                 + bfpick(yb[48 + p], odd) * eav[3];
        acc1 += w1 * d1;

        float d2 = bfpick(yb[64 + p], odd) * eav[4]
                 + bfpick(yb[80 + p], odd) * eav[5]
                 + bfpick(yb[96 + p], odd) * eav[6]
                 + bfpick(yb[112 + p], odd) * eav[7]
                 + bfpick(yb[128 + p], odd) * eav[8];
        acc2 += w2 * d2;
    }

    float* midRow = mid + (long)n * 96;
    midRow[u]      = acc0 * invAVG;
    midRow[32 + u] = acc1 * c1;
    midRow[64 + u] = acc2 * c2;
}

// ---------------------------------------------------------------------------
// Kernel C: output GEMV + sc + silu. float4 staging.
// ---------------------------------------------------------------------------
__global__ __launch_bounds__(256) void node_out(
    const float* __restrict__ mid,
    const float* __restrict__ sc,
    const float* __restrict__ L0,
    const float* __restrict__ L1,
    const float* __restrict__ L2,
    float* __restrict__ out)
{
    __shared__ float l0[32 * 32];
    __shared__ float l1[64 * 32];
    __shared__ float l2[96 * 32];
    __shared__ float ms[8][96];
    const int tid = threadIdx.x;
    const int nodeBase = blockIdx.x * 8;

    if (tid < 256) ((float4*)l0)[tid] = ((const float4*)L0)[tid];
    for (int i = tid; i < 512; i += 256) ((float4*)l1)[i] = ((const float4*)L1)[i];
    for (int i = tid; i < 768; i += 256) ((float4*)l2)[i] = ((const float4*)L2)[i];
    for (int i = tid; i < 192; i += 256) {
        int nl = i / 24, q = i % 24;
        int n = nodeBase + nl;
        float4 v = {0.f, 0.f, 0.f, 0.f};
        if (n < NN) v = ((const float4*)(mid + (long)n * 96))[q];
        ((float4*)ms[nl])[q] = v;
    }
    __syncthreads();

    const int nl = tid >> 5, wv = tid & 31;
    const int n = nodeBase + nl;
    if (n >= NN) return;

    float a0 = 0.f, a1 = 0.f, a2 = 0.f;
    #pragma unroll
    for (int u = 0; u < 32; ++u) {
        float m = ms[nl][u];
        a0 += m * l0[u * 32 + wv];
        a1 += m * l1[u * 32 + wv];
        a2 += m * l2[u * 32 + wv];
    }
    #pragma unroll
    for (int u = 32; u < 64; ++u) {
        float m = ms[nl][u];
        a1 += m * l1[u * 32 + wv];
        a2 += m * l2[u * 32 + wv];
    }
    #pragma unroll
    for (int u = 64; u < 96; ++u) a2 += ms[nl][u] * l2[u * 32 + wv];

    const float is32 = 0.17677669529663687f;
    const float is64 = 0.125f;
    const float is96 = 0.10206207261596575f;
    const long base = (long)n * 32 + wv;
    out[base]                     = silu_f(a0 * is32 + sc[base]);
    out[(long)NN * 32 + base]     = silu_f(a1 * is64 + sc[(long)NN * 32 + base]);
    out[(long)2 * NN * 32 + base] = silu_f(a2 * is96 + sc[(long)2 * NN * 32 + base]);
}

extern "C" void kernel_launch(void* const* d_in, const int* in_sizes, int n_in,
                              void* d_out, int out_size, void* d_ws, size_t ws_size,
                              hipStream_t stream)
{
    const float* x   = (const float*)d_in[0];
    const float* na  = (const float*)d_in[1];
    const float* ee  = (const float*)d_in[2];
    const float* ea  = (const float*)d_in[3];
    const int*   ei  = (const int*)d_in[4];
    const float* W10 = (const float*)d_in[5];
    const float* W11 = (const float*)d_in[6];
    const float* W12 = (const float*)d_in[7];
    const float* Wm0 = (const float*)d_in[8];
    const float* Wm1 = (const float*)d_in[9];
    const float* L0  = (const float*)d_in[10];
    const float* L1  = (const float*)d_in[11];
    const float* L2  = (const float*)d_in[12];
    const float* scW = (const float*)d_in[13];
    float* out = (float*)d_out;

    unsigned int* yAll16 = (unsigned int*)d_ws;           // NN*144 uints
    float* sc      = (float*)(yAll16 + (size_t)NN * 144); // 3*NN*32 f32
    float* mid     = sc + (size_t)3 * NN * 32;            // NN*96 f32
    int*   counts  = (int*)(mid + (size_t)NN * 96);       // NN  \ one memset
    int*   cursor  = counts + NN;                         // NN  /
    int*   offsets = cursor + NN;                         // NN+1
    int*   sidx    = offsets + NN + 1;                    // NE
    int*   ssrc    = sidx + NE;                           // NE
    unsigned int* wm1fg = (unsigned int*)(ssrc + NE);     // 3072
    unsigned int* wbuf  = wm1fg + 3072;                   // NE*48 uints (123 MB)

    hipMemsetAsync(counts, 0, 2 * NN * sizeof(int), stream);

    hist_kernel<<<(NE + 255) / 256, 256, 0, stream>>>(ei, counts);
    scan_kernel<<<1, 1024, 0, stream>>>(counts, offsets);
    scatter_ids<<<(NE + 255) / 256, 256, 0, stream>>>(ei, offsets, cursor, sidx, ssrc);

    prep_frags<<<24, 256, 0, stream>>>(Wm1, wm1fg);
    node_y<<<(NN + 7) / 8, 256, 0, stream>>>(x, W10, W11, W12, yAll16);
    node_sc<<<(NN + 63) / 64, 256, 0, stream>>>(x, na, scW, sc);

    edge_w<<<NE / 128, 256, 0, stream>>>(ee, sidx, Wm0, wm1fg, wbuf);
    gather_reduce<<<(NN + 7) / 8, 256, 0, stream>>>(wbuf, ea, ssrc, yAll16, sidx,
                                                    offsets, mid);

    node_out<<<(NN + 7) / 8, 256, 0, stream>>>(mid, sc, L0, L1, L2, out);
}

// Round 11
// 453.037 us; speedup vs baseline: 1.3248x; 1.0257x over previous
//
#include <hip/hip_runtime.h>
#include <hip/hip_bf16.h>

#define NN 20000
#define NE 640000

typedef __attribute__((ext_vector_type(8))) short short8v;   // 8 bf16
typedef __attribute__((ext_vector_type(4))) float float4v;

__device__ __forceinline__ float silu_f(float x) {
    return x / (1.0f + __expf(-x));
}

__device__ __forceinline__ unsigned int f2bf16(float f) {
    __hip_bfloat16 b = __float2bfloat16(f);
    return (unsigned int)*(unsigned short*)&b;
}

__device__ __forceinline__ float bfpick(unsigned int v, bool odd) {
    return odd ? __uint_as_float(v & 0xffff0000u) : __uint_as_float(v << 16);
}

// ---------------------------------------------------------------------------
// prep_frags: Wm1 -> bf16 B-fragment image (0.125 folded), computed ONCE.
// ---------------------------------------------------------------------------
__global__ __launch_bounds__(256) void prep_frags(
    const float* __restrict__ Wm1, unsigned int* __restrict__ wm1fg)
{
    int idx = blockIdx.x * 256 + threadIdx.x;     // 0..6143
    int j = idx & 7, lane = (idx >> 3) & 63, sec = idx >> 9;
    int kh = sec / 6, nt = sec % 6;
    int k = kh * 32 + ((lane >> 4) * 8) + j;
    int n = nt * 16 + (lane & 15);
    unsigned int b = f2bf16(Wm1[k * 96 + n] * 0.125f);
    unsigned int other = (unsigned int)__shfl_xor((int)b, 1);
    if ((idx & 1) == 0) wm1fg[idx >> 1] = b | (other << 16);
}

// ---------------------------------------------------------------------------
// Kernel A1: per-node y precompute -> PACKED BF16, plane-major (144 uints).
// ---------------------------------------------------------------------------
__global__ __launch_bounds__(256) void node_y(
    const float* __restrict__ x,
    const float* __restrict__ W10,
    const float* __restrict__ W11,
    const float* __restrict__ W12,
    unsigned int* __restrict__ yAll16)
{
    __shared__ float xs[8][288];
    __shared__ float w10[1024];
    __shared__ float w11[1024];
    __shared__ float w12[1024];
    const int tid = threadIdx.x;
    const int nodeBase = blockIdx.x * 8;

    if (tid < 256) {
        ((float4*)w10)[tid] = ((const float4*)W10)[tid];
        ((float4*)w11)[tid] = ((const float4*)W11)[tid];
        ((float4*)w12)[tid] = ((const float4*)W12)[tid];
    }
    for (int i = tid; i < 576; i += 256) {
        int nl = i / 72, q = i % 72;
        int n = nodeBase + nl;
        float4 v = {0.f, 0.f, 0.f, 0.f};
        if (n < NN) v = ((const float4*)(x + (long)n * 288))[q];
        ((float4*)xs[nl])[q] = v;
    }
    __syncthreads();

    const int nl = tid >> 5, v = tid & 31;
    const int n = nodeBase + nl;
    if (n >= NN) return;

    const float inv_mul = 0.17677669529663687f;  // 1/sqrt(32)
    float vals[9];

    {
        float a = 0.f;
        #pragma unroll
        for (int u = 0; u < 32; ++u) a += xs[nl][u] * w10[u * 32 + v];
        vals[0] = a;
    }
    {
        float a0 = 0.f, a1 = 0.f, a2 = 0.f;
        #pragma unroll
        for (int u = 0; u < 32; ++u) {
            float wv = w11[u * 32 + v];
            a0 += xs[nl][32 + u * 3 + 0] * wv;
            a1 += xs[nl][32 + u * 3 + 1] * wv;
            a2 += xs[nl][32 + u * 3 + 2] * wv;
        }
        vals[1] = a0; vals[2] = a1; vals[3] = a2;
    }
    {
        float a[5] = {0.f, 0.f, 0.f, 0.f, 0.f};
        #pragma unroll
        for (int u = 0; u < 32; ++u) {
            float wv = w12[u * 32 + v];
            #pragma unroll
            for (int m = 0; m < 5; ++m) a[m] += xs[nl][128 + u * 5 + m] * wv;
        }
        #pragma unroll
        for (int m = 0; m < 5; ++m) vals[4 + m] = a[m];
    }

    unsigned int* yrow = yAll16 + (long)n * 144;
    const bool evenLane = ((v & 1) == 0);
    #pragma unroll
    for (int pl = 0; pl < 9; ++pl) {
        float mine  = vals[pl] * inv_mul;
        float other = __shfl_xor(mine, 1);
        if (evenLane)
            yrow[pl * 16 + (v >> 1)] = f2bf16(mine) | (f2bf16(other) << 16);
    }
}

// ---------------------------------------------------------------------------
// Kernel A2: sc GEMM. 64 nodes/block; thread = 8 nodes x 3 cols.
// ---------------------------------------------------------------------------
__global__ __launch_bounds__(256) void node_sc(
    const float* __restrict__ x,
    const float* __restrict__ na,
    const float* __restrict__ scW,
    float* __restrict__ sc)
{
    __shared__ float B[128 * 96];
    __shared__ float x0s[64 * 32];
    __shared__ float nas[64 * 4];
    const int tid = threadIdx.x;
    const int nodeBase = blockIdx.x * 64;

    for (int i = tid; i < 3072; i += 256) {
        int qw = i & 7, rest = i >> 3;
        int t = rest & 3, u = (rest >> 2) & 31, h = rest >> 7;
        float4 v = ((const float4*)scW)[i];
        ((float4*)&B[(u * 4 + t) * 96 + h * 32])[qw] = v;
    }
    for (int i = tid; i < 512; i += 256) {
        int nl = i >> 3, q = i & 7;
        int n = nodeBase + nl;
        float4 v = {0.f, 0.f, 0.f, 0.f};
        if (n < NN) v = ((const float4*)(x + (long)n * 288))[q];
        ((float4*)&x0s[nl * 32])[q] = v;
    }
    for (int i = tid; i < 256; i += 256) {
        int nl = i >> 2, t = i & 3;
        int n = nodeBase + nl;
        nas[i] = (n < NN) ? na[n * 4 + t] : 0.f;
    }
    __syncthreads();

    const int g = tid >> 5, c = tid & 31;
    float nav[8][4];
    #pragma unroll
    for (int j = 0; j < 8; ++j)
        #pragma unroll
        for (int t = 0; t < 4; ++t) nav[j][t] = nas[(g * 8 + j) * 4 + t];

    float acc[3][8];
    #pragma unroll
    for (int cc = 0; cc < 3; ++cc)
        #pragma unroll
        for (int j = 0; j < 8; ++j) acc[cc][j] = 0.f;

    for (int u = 0; u < 32; ++u) {
        float aj[8];
        #pragma unroll
        for (int j = 0; j < 8; ++j) aj[j] = x0s[(g * 8 + j) * 32 + u];
        #pragma unroll
        for (int t = 0; t < 4; ++t) {
            float b0 = B[(u * 4 + t) * 96 + c];
            float b1 = B[(u * 4 + t) * 96 + 32 + c];
            float b2 = B[(u * 4 + t) * 96 + 64 + c];
            #pragma unroll
            for (int j = 0; j < 8; ++j) {
                float p = aj[j] * nav[j][t];
                acc[0][j] += p * b0;
                acc[1][j] += p * b1;
                acc[2][j] += p * b2;
            }
        }
    }

    const float inv_sc = 0.08838834764831845f;  // 1/sqrt(128)
    #pragma unroll
    for (int j = 0; j < 8; ++j) {
        int n = nodeBase + g * 8 + j;
        if (n < NN) {
            #pragma unroll
            for (int cc = 0; cc < 3; ++cc)
                sc[((long)cc * NN + n) * 32 + c] = acc[cc][j] * inv_sc;
        }
    }
}

// ---------------------------------------------------------------------------
// CSR build (dest): histogram -> scan -> scatter ids (+ sorted source).
// ---------------------------------------------------------------------------
__global__ __launch_bounds__(256) void hist_kernel(
    const int* __restrict__ ei, int* __restrict__ counts)
{
    int e = blockIdx.x * 256 + threadIdx.x;
    if (e < NE) atomicAdd(&counts[ei[NE + e]], 1);
}

__global__ __launch_bounds__(1024) void scan_kernel(
    const int* __restrict__ counts, int* __restrict__ offsets)
{
    __shared__ int partial[1024];
    const int t = threadIdx.x;
    const int base = t * 20;          // 1024*20 = 20480 >= NN
    int loc[20];
    int s = 0;
    #pragma unroll
    for (int i = 0; i < 20; ++i) {
        int v = (base + i < NN) ? counts[base + i] : 0;
        loc[i] = s;
        s += v;
    }
    partial[t] = s;
    __syncthreads();
    for (int off = 1; off < 1024; off <<= 1) {
        int v = (t >= off) ? partial[t - off] : 0;
        __syncthreads();
        partial[t] += v;
        __syncthreads();
    }
    int pre = (t == 0) ? 0 : partial[t - 1];
    #pragma unroll
    for (int i = 0; i < 20; ++i)
        if (base + i <= NN) offsets[base + i] = pre + loc[i];
}

__global__ __launch_bounds__(256) void scatter_ids(
    const int* __restrict__ ei, const int* __restrict__ offsets,
    int* __restrict__ cursor, int* __restrict__ sidx, int* __restrict__ ssrc)
{
    int e = blockIdx.x * 256 + threadIdx.x;
    if (e < NE) {
        int d = ei[NE + e];
        int s = ei[e];
        int pos = offsets[d] + atomicAdd(&cursor[d], 1);
        sidx[pos] = e;
        ssrc[pos] = s;
    }
}

// ---------------------------------------------------------------------------
// Kernel B1 (MFMA): w = silu(ee@Wm0/sqrt8) @ Wm1 * 0.125 for 64 sorted
// positions per block. 36 KB LDS -> 4 blocks/CU (the 128-tile variant at
// 59 KB dropped to 2 blocks/CU and went latency-bound — R10). Wm1 fragments
// precomputed by prep_frags -> per-block staging is a pure 12 KB copy.
// ---------------------------------------------------------------------------
__global__ __launch_bounds__(256) void edge_w(
    const float* __restrict__ ee,
    const int*   __restrict__ sidx,
    const float* __restrict__ Wm0,
    const unsigned int* __restrict__ wm1fg,
    unsigned int* __restrict__ w)
{
    __shared__ float ees[64 * 8];                 // [le*8 + k]   2 KB
    __shared__ float wm0s[512];                   // [k*64 + i]   2 KB
    __shared__ unsigned short hsf[8 * 64 * 8];    // A-frags      8 KB
    __shared__ unsigned int wm1u[3072];           // B-frags     12 KB
    __shared__ unsigned int wtile[64 * 48];       // D packed    12 KB

    const int tid = threadIdx.x;
    const long pb = (long)blockIdx.x * 64;        // sorted position base

    for (int i = tid; i < 512; i += 256) wm0s[i] = Wm0[i];
    for (int i = tid; i < 3072; i += 256) wm1u[i] = wm1fg[i];
    for (int i = tid; i < 512; i += 256) {
        int le = i >> 3, k = i & 7;
        int e = sidx[pb + le];
        ees[i] = ee[(long)e * 8 + k];
    }
    __syncthreads();

    // phase 1: h -> A-frag slots (bf16). thread = (edge, quarter)
    {
        const float inv_sqrt8 = 0.35355339059327373f;
        const int e = tid >> 2, i0 = (tid & 3) * 16;
        const int tile = e >> 4, m = e & 15;
        float emb[8];
        #pragma unroll
        for (int k = 0; k < 8; ++k) emb[k] = ees[e * 8 + k];
        #pragma unroll
        for (int i = 0; i < 16; ++i) {
            int k = i0 + i;
            float t = 0.f;
            #pragma unroll
            for (int q = 0; q < 8; ++q) t += emb[q] * wm0s[q * 64 + k];
            int kh = k >> 5, kq = (k >> 3) & 3, j = k & 7;
            int lane = kq * 16 + m;
            hsf[((tile * 2 + kh) * 64 + lane) * 8 + j] =
                (unsigned short)f2bf16(silu_f(t * inv_sqrt8));
        }
    }
    __syncthreads();

    // phase 2: MFMA. wave wv -> edge-tile wv x 6 channel-tiles.
    {
        unsigned short* wts = (unsigned short*)wtile;
        const unsigned short* wm1f = (const unsigned short*)wm1u;
        const int wv = tid >> 6, lane = tid & 63;
        const short8v a0 = *(const short8v*)&hsf[((wv * 2 + 0) * 64 + lane) * 8];
        const short8v a1 = *(const short8v*)&hsf[((wv * 2 + 1) * 64 + lane) * 8];
        const int col = lane & 15, rowq = (lane >> 4) * 4;
        #pragma unroll
        for (int nt = 0; nt < 6; ++nt) {
            short8v b0 = *(const short8v*)&wm1f[((0 * 6 + nt) * 64 + lane) * 8];
            short8v b1 = *(const short8v*)&wm1f[((1 * 6 + nt) * 64 + lane) * 8];
            float4v acc = {0.f, 0.f, 0.f, 0.f};
            acc = __builtin_amdgcn_mfma_f32_16x16x32_bf16(a0, b0, acc, 0, 0, 0);
            acc = __builtin_amdgcn_mfma_f32_16x16x32_bf16(a1, b1, acc, 0, 0, 0);
            const int c = nt * 16 + col;
            #pragma unroll
            for (int r = 0; r < 4; ++r)
                wts[(wv * 16 + rowq + r) * 96 + c] = (unsigned short)f2bf16(acc[r]);
        }
    }
    __syncthreads();

    // copy-out: 64 rows x 48 uints, coalesced, contiguous at sorted base
    for (int i = tid; i < 3072; i += 256)
        w[pb * 48 + i] = wtile[i];
}

// ---------------------------------------------------------------------------
// Kernel B2: single-pass atomic-free gather-reduce (R8-proven).
// ---------------------------------------------------------------------------
__global__ __launch_bounds__(256) void gather_reduce(
    const unsigned int* __restrict__ w,
    const float* __restrict__ ea,
    const int*   __restrict__ ssrc,
    const unsigned int* __restrict__ yAll16,
    const int*   __restrict__ sidx,
    const int*   __restrict__ offsets,
    float* __restrict__ mid)
{
    const int tid = threadIdx.x;
    const int n = blockIdx.x * 8 + (tid >> 5);
    const int u = tid & 31;
    if (n >= NN) return;

    const int lo = offsets[n], hi = offsets[n + 1];

    const float invAVG = 0.17677669529663687f;                        // 1/sqrt(32)
    const float c1     = 0.5773502691896258f * 0.17677669529663687f;  // /sqrt3/sqrt32
    const float c2     = 0.4472135954999579f * 0.17677669529663687f;  // /sqrt5/sqrt32

    const int p = u >> 1;
    const bool odd = (u & 1);

    float acc0 = 0.f, acc1 = 0.f, acc2 = 0.f;
    #pragma unroll 2
    for (int j = lo; j < hi; ++j) {
        const int e = sidx[j];
        const int s = ssrc[j];
        const unsigned int* wr = w + (long)j * 48;
        const unsigned int* yb = yAll16 + (long)s * 144;
        const float* eav = ea + (long)e * 9;

        float w0 = bfpick(wr[p], odd);
        float w1 = bfpick(wr[16 + p], odd);
        float w2 = bfpick(wr[32 + p], odd);

        acc0 += w0 * bfpick(yb[p], odd) * eav[0];

        float d1 = bfpick(yb[16 + p], odd) * eav[1]
                 + bfpick(yb[32 + p], odd) * eav[2]
                 + bfpick(yb[48 + p], odd) * eav[3];
        acc1 += w1 * d1;

        float d2 = bfpick(yb[64 + p], odd) * eav[4]
                 + bfpick(yb[80 + p], odd) * eav[5]
                 + bfpick(yb[96 + p], odd) * eav[6]
                 + bfpick(yb[112 + p], odd) * eav[7]
                 + bfpick(yb[128 + p], odd) * eav[8];
        acc2 += w2 * d2;
    }

    float* midRow = mid + (long)n * 96;
    midRow[u]      = acc0 * invAVG;
    midRow[32 + u] = acc1 * c1;
    midRow[64 + u] = acc2 * c2;
}

// ---------------------------------------------------------------------------
// Kernel C: output GEMV + sc + silu. float4 staging.
// ---------------------------------------------------------------------------
__global__ __launch_bounds__(256) void node_out(
    const float* __restrict__ mid,
    const float* __restrict__ sc,
    const float* __restrict__ L0,
    const float* __restrict__ L1,
    const float* __restrict__ L2,
    float* __restrict__ out)
{
    __shared__ float l0[32 * 32];
    __shared__ float l1[64 * 32];
    __shared__ float l2[96 * 32];
    __shared__ float ms[8][96];
    const int tid = threadIdx.x;
    const int nodeBase = blockIdx.x * 8;

    if (tid < 256) ((float4*)l0)[tid] = ((const float4*)L0)[tid];
    for (int i = tid; i < 512; i += 256) ((float4*)l1)[i] = ((const float4*)L1)[i];
    for (int i = tid; i < 768; i += 256) ((float4*)l2)[i] = ((const float4*)L2)[i];
    for (int i = tid; i < 192; i += 256) {
        int nl = i / 24, q = i % 24;
        int n = nodeBase + nl;
        float4 v = {0.f, 0.f, 0.f, 0.f};
        if (n < NN) v = ((const float4*)(mid + (long)n * 96))[q];
        ((float4*)ms[nl])[q] = v;
    }
    __syncthreads();

    const int nl = tid >> 5, wv = tid & 31;
    const int n = nodeBase + nl;
    if (n >= NN) return;

    float a0 = 0.f, a1 = 0.f, a2 = 0.f;
    #pragma unroll
    for (int u = 0; u < 32; ++u) {
        float m = ms[nl][u];
        a0 += m * l0[u * 32 + wv];
        a1 += m * l1[u * 32 + wv];
        a2 += m * l2[u * 32 + wv];
    }
    #pragma unroll
    for (int u = 32; u < 64; ++u) {
        float m = ms[nl][u];
        a1 += m * l1[u * 32 + wv];
        a2 += m * l2[u * 32 + wv];
    }
    #pragma unroll
    for (int u = 64; u < 96; ++u) a2 += ms[nl][u] * l2[u * 32 + wv];

    const float is32 = 0.17677669529663687f;
    const float is64 = 0.125f;
    const float is96 = 0.10206207261596575f;
    const long base = (long)n * 32 + wv;
    out[base]                     = silu_f(a0 * is32 + sc[base]);
    out[(long)NN * 32 + base]     = silu_f(a1 * is64 + sc[(long)NN * 32 + base]);
    out[(long)2 * NN * 32 + base] = silu_f(a2 * is96 + sc[(long)2 * NN * 32 + base]);
}

extern "C" void kernel_launch(void* const* d_in, const int* in_sizes, int n_in,
                              void* d_out, int out_size, void* d_ws, size_t ws_size,
                              hipStream_t stream)
{
    const float* x   = (const float*)d_in[0];
    const float* na  = (const float*)d_in[1];
    const float* ee  = (const float*)d_in[2];
    const float* ea  = (const float*)d_in[3];
    const int*   ei  = (const int*)d_in[4];
    const float* W10 = (const float*)d_in[5];
    const float* W11 = (const float*)d_in[6];
    const float* W12 = (const float*)d_in[7];
    const float* Wm0 = (const float*)d_in[8];
    const float* Wm1 = (const float*)d_in[9];
    const float* L0  = (const float*)d_in[10];
    const float* L1  = (const float*)d_in[11];
    const float* L2  = (const float*)d_in[12];
    const float* scW = (const float*)d_in[13];
    float* out = (float*)d_out;

    unsigned int* yAll16 = (unsigned int*)d_ws;           // NN*144 uints
    float* sc      = (float*)(yAll16 + (size_t)NN * 144); // 3*NN*32 f32
    float* mid     = sc + (size_t)3 * NN * 32;            // NN*96 f32
    int*   counts  = (int*)(mid + (size_t)NN * 96);       // NN  \ one memset
    int*   cursor  = counts + NN;                         // NN  /
    int*   offsets = cursor + NN;                         // NN+1
    int*   sidx    = offsets + NN + 1;                    // NE
    int*   ssrc    = sidx + NE;                           // NE
    unsigned int* wm1fg = (unsigned int*)(ssrc + NE);     // 3072
    unsigned int* wbuf  = wm1fg + 3072;                   // NE*48 uints (123 MB)

    hipMemsetAsync(counts, 0, 2 * NN * sizeof(int), stream);

    hist_kernel<<<(NE + 255) / 256, 256, 0, stream>>>(ei, counts);
    scan_kernel<<<1, 1024, 0, stream>>>(counts, offsets);
    scatter_ids<<<(NE + 255) / 256, 256, 0, stream>>>(ei, offsets, cursor, sidx, ssrc);

    prep_frags<<<24, 256, 0, stream>>>(Wm1, wm1fg);
    node_y<<<(NN + 7) / 8, 256, 0, stream>>>(x, W10, W11, W12, yAll16);
    node_sc<<<(NN + 63) / 64, 256, 0, stream>>>(x, na, scW, sc);

    edge_w<<<NE / 64, 256, 0, stream>>>(ee, sidx, Wm0, wm1fg, wbuf);
    gather_reduce<<<(NN + 7) / 8, 256, 0, stream>>>(wbuf, ea, ssrc, yAll16, sidx,
                                                    offsets, mid);

    node_out<<<(NN + 7) / 8, 256, 0, stream>>>(mid, sc, L0, L1, L2, out);
}